// Round 1
// baseline (1428.403 us; speedup 1.0000x reference)
//
#include <hip/hip_runtime.h>
#include <cstddef>
#include <cstdint>

#define NN 50000   // nodes
#define EE 640000  // edges
#define FD 128     // feature dim (F_IN == DIM == 128)

// ================= CSR build (counting sort by dst) =================
// deg/off/cursor/sorted_src live in the tail of the outE region of d_out:
// they are dead before k_edge overwrites that region.

__global__ __launch_bounds__(256) void k_zero(int* __restrict__ p) {
  int i = blockIdx.x * 256 + threadIdx.x;
  if (i < NN) p[i] = 0;
}

__global__ __launch_bounds__(256) void k_hist(const int* __restrict__ dst,
                                              int* __restrict__ deg) {
  int e = blockIdx.x * 256 + threadIdx.x;  // grid = EE/256 exact
  atomicAdd(&deg[dst[e]], 1);
}

// single-block exclusive scan of deg[NN] -> off, cursor. 4 elems/thread,
// wave-shuffle scan + 16-wave LDS combine; 13 chunks of 4096.
__global__ __launch_bounds__(1024) void k_scan(const int* __restrict__ deg,
                                               int* __restrict__ off,
                                               int* __restrict__ cur) {
  __shared__ int wsum[16], woff[16];
  __shared__ int carryS;
  const int t = threadIdx.x, lane = t & 63, w = t >> 6;
  if (t == 0) carryS = 0;
  __syncthreads();
  for (int base = 0; base < NN; base += 4096) {
    int i = base + (t << 2);
    int4 dv = make_int4(0, 0, 0, 0);
    if (i < NN) dv = *reinterpret_cast<const int4*>(deg + i);  // NN%4==0, aligned
    int tsum = dv.x + dv.y + dv.z + dv.w;
    int incl = tsum;
#pragma unroll
    for (int d = 1; d < 64; d <<= 1) {
      int u = __shfl_up(incl, d, 64);
      if (lane >= d) incl += u;
    }
    if (lane == 63) wsum[w] = incl;
    __syncthreads();
    if (t == 0) {
      int run = 0;
#pragma unroll
      for (int k = 0; k < 16; ++k) { woff[k] = run; run += wsum[k]; }
    }
    __syncthreads();
    int ebase = (incl - tsum) + woff[w] + carryS;
    if (i < NN) {
      int4 ov;
      ov.x = ebase;
      ov.y = ebase + dv.x;
      ov.z = ov.y + dv.y;
      ov.w = ov.z + dv.z;
      *reinterpret_cast<int4*>(off + i) = ov;
      *reinterpret_cast<int4*>(cur + i) = ov;
    }
    __syncthreads();
    if (t == 0) carryS += woff[15] + wsum[15];
    __syncthreads();
  }
}

__global__ __launch_bounds__(256) void k_fill(const int* __restrict__ src,
                                              const int* __restrict__ dst,
                                              int* __restrict__ cur,
                                              int* __restrict__ ssrc) {
  int e = blockIdx.x * 256 + threadIdx.x;  // grid = EE/256 exact
  int d = dst[e];
  int pos = atomicAdd(&cur[d], 1);
  ssrc[pos] = src[e];
}

// ============ aggregation: agg[i] = h[i] + sum_{j in in(i)} h[j] ============
// half-wave (32 lanes) per node, float4 per lane; zero atomics.
__global__ __launch_bounds__(256) void k_agg(const float* __restrict__ h,
                                             const int* __restrict__ off,
                                             const int* __restrict__ deg,
                                             const int* __restrict__ ssrc,
                                             float* __restrict__ agg) {
  int node = blockIdx.x * 8 + (threadIdx.x >> 5);  // grid = NN/8 exact
  int lane = threadIdx.x & 31;
  int f = lane << 2;
  float4 acc = *reinterpret_cast<const float4*>(h + (size_t)node * FD + f);  // self term
  int n = deg[node];
  const int* sl = ssrc + off[node];
  int j = 0;
  for (; j + 4 <= n; j += 4) {
    int s0 = sl[j], s1 = sl[j + 1], s2 = sl[j + 2], s3 = sl[j + 3];
    float4 v0 = *reinterpret_cast<const float4*>(h + (size_t)s0 * FD + f);
    float4 v1 = *reinterpret_cast<const float4*>(h + (size_t)s1 * FD + f);
    float4 v2 = *reinterpret_cast<const float4*>(h + (size_t)s2 * FD + f);
    float4 v3 = *reinterpret_cast<const float4*>(h + (size_t)s3 * FD + f);
    acc.x += (v0.x + v1.x) + (v2.x + v3.x);
    acc.y += (v0.y + v1.y) + (v2.y + v3.y);
    acc.z += (v0.z + v1.z) + (v2.z + v3.z);
    acc.w += (v0.w + v1.w) + (v2.w + v3.w);
  }
  for (; j < n; ++j) {
    int s = sl[j];
    float4 v = *reinterpret_cast<const float4*>(h + (size_t)s * FD + f);
    acc.x += v.x; acc.y += v.y; acc.z += v.z; acc.w += v.w;
  }
  *reinterpret_cast<float4*>(agg + (size_t)node * FD + f) = acc;
}

// ---------------- fused GEMM: O = relu(opt_bn(A @ W + b)) ----------------
__global__ __launch_bounds__(256) void k_gemm(const float* __restrict__ A,
                                              const float* __restrict__ W,
                                              const float* __restrict__ bias,
                                              const float* __restrict__ gg,
                                              const float* __restrict__ bb,
                                              const float* __restrict__ rm,
                                              const float* __restrict__ rv,
                                              int use_bn,
                                              float* __restrict__ O, int M) {
  __shared__ float At[64][68];   // [k][r], pad 68 to spread store banks
  __shared__ float Ws[64][132];  // [k][c], pad 132 -> conflict-free b128 reads
  const int t  = threadIdx.x;
  const int tx = t & 15;   // col group: cols tx*8 .. tx*8+7
  const int ty = t >> 4;   // row group: rows ty*4 .. ty*4+3
  const int rowBase = blockIdx.x * 64;

  float acc[4][8] = {};

  for (int kc = 0; kc < 2; ++kc) {
    const int k0 = kc * 64;
#pragma unroll
    for (int i = 0; i < 4; ++i) {
      int idx = t + i * 256;
      int row = idx >> 4;
      int kg  = (idx & 15) << 2;
      int r = rowBase + row;
      float4 v = make_float4(0.f, 0.f, 0.f, 0.f);
      if (r < M) v = *reinterpret_cast<const float4*>(A + (size_t)r * FD + k0 + kg);
      At[kg + 0][row] = v.x;
      At[kg + 1][row] = v.y;
      At[kg + 2][row] = v.z;
      At[kg + 3][row] = v.w;
    }
#pragma unroll
    for (int i = 0; i < 8; ++i) {
      int idx = t + i * 256;
      int wr = idx >> 5;
      int wc = (idx & 31) << 2;
      *reinterpret_cast<float4*>(&Ws[wr][wc]) =
          *reinterpret_cast<const float4*>(W + (size_t)(k0 + wr) * FD + wc);
    }
    __syncthreads();

#pragma unroll 8
    for (int k = 0; k < 64; ++k) {
      const float4 a  = *reinterpret_cast<const float4*>(&At[k][ty << 2]);
      const float4 w0 = *reinterpret_cast<const float4*>(&Ws[k][tx << 3]);
      const float4 w1 = *reinterpret_cast<const float4*>(&Ws[k][(tx << 3) + 4]);
      const float av[4] = {a.x, a.y, a.z, a.w};
      const float wv[8] = {w0.x, w0.y, w0.z, w0.w, w1.x, w1.y, w1.z, w1.w};
#pragma unroll
      for (int i = 0; i < 4; ++i)
#pragma unroll
        for (int j = 0; j < 8; ++j)
          acc[i][j] = fmaf(av[i], wv[j], acc[i][j]);
    }
    __syncthreads();
  }

  const int c0 = tx << 3;
  float sc[8], sh[8];
#pragma unroll
  for (int j = 0; j < 8; ++j) {
    int c = c0 + j;
    if (use_bn) {
      float s = gg[c] * rsqrtf(rv[c] + 1e-5f);
      sc[j] = s;
      sh[j] = (bias[c] - rm[c]) * s + bb[c];
    } else {
      sc[j] = 1.f;
      sh[j] = bias[c];
    }
  }
#pragma unroll
  for (int i = 0; i < 4; ++i) {
    int r = rowBase + (ty << 2) + i;
    if (r < M) {
      float o[8];
#pragma unroll
      for (int j = 0; j < 8; ++j) {
        float v = fmaf(acc[i][j], sc[j], sh[j]);
        o[j] = v > 0.f ? v : 0.f;
      }
      *reinterpret_cast<float4*>(O + (size_t)r * FD + c0) =
          make_float4(o[0], o[1], o[2], o[3]);
      *reinterpret_cast<float4*>(O + (size_t)r * FD + c0 + 4) =
          make_float4(o[4], o[5], o[6], o[7]);
    }
  }
}

// ---------------- U/V: per-node logit halves ----------------
__global__ __launch_bounds__(256) void k_uv(const float* __restrict__ h,
                                            const float* __restrict__ clsW,
                                            float* __restrict__ U,
                                            float* __restrict__ V) {
  int t = blockIdx.x * 256 + threadIdx.x;
  int r = t / 12;
  int c = t % 12;
  if (r >= NN) return;
  int cc = (c < 6) ? c : c - 6;
  int base = (c < 6) ? 0 : FD;
  const float* hr = h + (size_t)r * FD;
  float acc = 0.f;
#pragma unroll 8
  for (int k = 0; k < FD; ++k)
    acc = fmaf(hr[k], clsW[(size_t)(base + k) * 6 + cc], acc);
  if (c < 6) U[(size_t)r * 6 + cc] = acc;
  else       V[(size_t)r * 6 + cc] = acc;
}

// ---------------- edge kernel ----------------
__global__ __launch_bounds__(256) void k_edge(const float* __restrict__ h,
                                              const int* __restrict__ src,
                                              const int* __restrict__ dst,
                                              const float* __restrict__ U,
                                              const float* __restrict__ V,
                                              const float* __restrict__ clsB,
                                              float* __restrict__ outL,
                                              float* __restrict__ outE) {
  int eid  = blockIdx.x * 4 + (threadIdx.x >> 6);  // one wave per edge
  int lane = threadIdx.x & 63;
  int s = src[eid];
  int d = dst[eid];
  int node = (lane < 32) ? s : d;
  int f = (lane & 31) << 2;
  float4 v = *reinterpret_cast<const float4*>(h + (size_t)node * FD + f);
  *reinterpret_cast<float4*>(outE + (size_t)eid * 256 + (lane << 2)) = v;
  if (lane < 6)
    outL[(size_t)eid * 6 + lane] = U[(size_t)s * 6 + lane] + V[(size_t)d * 6 + lane] + clsB[lane];
}

extern "C" void kernel_launch(void* const* d_in, const int* in_sizes, int n_in,
                              void* d_out, int out_size, void* d_ws, size_t ws_size,
                              hipStream_t stream) {
  const float* x     = (const float*)d_in[0];
  const int*   ei    = (const int*)d_in[1];
  const int*   src   = ei;
  const int*   dst   = ei + EE;
  const float* c1_W1 = (const float*)d_in[3];
  const float* c1_b1 = (const float*)d_in[4];
  const float* c1_g  = (const float*)d_in[5];
  const float* c1_be = (const float*)d_in[6];
  const float* c1_rm = (const float*)d_in[7];
  const float* c1_rv = (const float*)d_in[8];
  const float* c1_W2 = (const float*)d_in[9];
  const float* c1_b2 = (const float*)d_in[10];
  const float* cv_W1 = (const float*)d_in[11];
  const float* cv_b1 = (const float*)d_in[12];
  const float* cv_g  = (const float*)d_in[13];
  const float* cv_be = (const float*)d_in[14];
  const float* cv_rm = (const float*)d_in[15];
  const float* cv_rv = (const float*)d_in[16];
  const float* cv_W2 = (const float*)d_in[17];
  const float* cv_b2 = (const float*)d_in[18];
  const float* ln_W  = (const float*)d_in[19];
  const float* ln_b  = (const float*)d_in[20];
  const float* clsW  = (const float*)d_in[21];
  const float* clsB  = (const float*)d_in[22];

  // workspace (unchanged from verified layout, ~53.6 MB):
  float* buf0 = (float*)d_ws;
  float* buf1 = buf0 + (size_t)NN * FD;
  float* Uu   = buf1 + (size_t)NN * FD;
  float* Vv   = Uu + (size_t)NN * 6;

  float* outL = (float*)d_out;
  float* outE = outL + (size_t)EE * 6;

  // CSR scratch in the tail of outE (dead before k_edge overwrites it):
  // deg[NN], off[NN], cursor[NN], sorted_src[EE] = ~3.2 MB
  const size_t outFloats = (size_t)EE * 262;
  const size_t scrInts   = (size_t)NN * 3 + (size_t)EE;
  const size_t scrStart  = (outFloats - scrInts) & ~(size_t)3;  // 16B align
  int* deg  = (int*)d_out + scrStart;
  int* off  = deg + NN;
  int* curp = off + NN;
  int* ssrc = curp + NN;

  dim3 B(256);
  const int gZero = (NN + 255) / 256;     // 196
  const int gEdgeWk = EE / 256;           // 2500 (exact)
  const int gAgg  = NN / 8;               // 6250 (exact)
  const int gGemm = (NN + 63) / 64;       // 782
  const int gUV   = (NN * 12 + 255) / 256;
  const int gEdge = EE / 4;               // 160000 (exact)

  // ---- build CSR (once per launch) ----
  k_zero<<<gZero, B, 0, stream>>>(deg);
  k_hist<<<gEdgeWk, B, 0, stream>>>(dst, deg);
  k_scan<<<1, dim3(1024), 0, stream>>>(deg, off, curp);
  k_fill<<<gEdgeWk, B, 0, stream>>>(src, dst, curp, ssrc);

  float* bufs[2] = {buf0, buf1};

  // conv1: agg = x + sum_in(x); z = relu(bn(agg@W1+b1)); h = relu(z@W2+b2)
  k_agg<<<gAgg, B, 0, stream>>>(x, off, deg, ssrc, buf0);
  k_gemm<<<gGemm, B, 0, stream>>>(buf0, c1_W1, c1_b1, c1_g, c1_be, c1_rm, c1_rv, 1, buf1, NN);
  k_gemm<<<gGemm, B, 0, stream>>>(buf1, c1_W2, c1_b2, nullptr, nullptr, nullptr, nullptr, 0, buf0, NN);
  int pp = 0;

  // 2 more GIN layers
  for (int l = 0; l < 2; ++l) {
    float* hc = bufs[pp];
    float* ho = bufs[1 - pp];
    k_agg<<<gAgg, B, 0, stream>>>(hc, off, deg, ssrc, ho);
    k_gemm<<<gGemm, B, 0, stream>>>(ho, cv_W1 + (size_t)l * FD * FD, cv_b1 + l * FD,
                                    cv_g + l * FD, cv_be + l * FD, cv_rm + l * FD,
                                    cv_rv + l * FD, 1, hc, NN);
    k_gemm<<<gGemm, B, 0, stream>>>(hc, cv_W2 + (size_t)l * FD * FD, cv_b2 + l * FD,
                                    nullptr, nullptr, nullptr, nullptr, 0, ho, NN);
    pp = 1 - pp;
  }

  // 2 linear layers
  for (int l = 0; l < 2; ++l) {
    k_gemm<<<gGemm, B, 0, stream>>>(bufs[pp], ln_W + (size_t)l * FD * FD, ln_b + l * FD,
                                    nullptr, nullptr, nullptr, nullptr, 0, bufs[1 - pp], NN);
    pp = 1 - pp;
  }

  // classifier split + edge materialization
  k_uv<<<gUV, B, 0, stream>>>(bufs[pp], clsW, Uu, Vv);
  k_edge<<<gEdge, B, 0, stream>>>(bufs[pp], src, dst, Uu, Vv, clsB, outL, outE);
}

// Round 3
// 1284.431 us; speedup vs baseline: 1.1121x; 1.1121x over previous
//
#include <hip/hip_runtime.h>
#include <cstddef>
#include <cstdint>

#define NN 50000   // nodes
#define EE 640000  // edges
#define FD 128     // feature dim (F_IN == DIM == 128)

typedef float fvec4 __attribute__((ext_vector_type(4)));  // native vec for nontemporal

// ================= CSR build (counting sort by dst) =================
// deg/off/cursor/sorted_src live in the tail of the outE region of d_out:
// they are dead before k_edge overwrites that region.

__global__ __launch_bounds__(256) void k_zero(int* __restrict__ p) {
  int i = blockIdx.x * 256 + threadIdx.x;
  if (i < NN) p[i] = 0;
}

__global__ __launch_bounds__(256) void k_hist(const int* __restrict__ dst,
                                              int* __restrict__ deg) {
  int e = blockIdx.x * 256 + threadIdx.x;  // grid = EE/256 exact
  atomicAdd(&deg[dst[e]], 1);
}

// single-block exclusive scan of deg[NN] -> off, cursor.
__global__ __launch_bounds__(1024) void k_scan(const int* __restrict__ deg,
                                               int* __restrict__ off,
                                               int* __restrict__ cur) {
  __shared__ int wsum[16], woff[16];
  __shared__ int carryS;
  const int t = threadIdx.x, lane = t & 63, w = t >> 6;
  if (t == 0) carryS = 0;
  __syncthreads();
  for (int base = 0; base < NN; base += 4096) {
    int i = base + (t << 2);
    int4 dv = make_int4(0, 0, 0, 0);
    if (i < NN) dv = *reinterpret_cast<const int4*>(deg + i);
    int tsum = dv.x + dv.y + dv.z + dv.w;
    int incl = tsum;
#pragma unroll
    for (int d = 1; d < 64; d <<= 1) {
      int u = __shfl_up(incl, d, 64);
      if (lane >= d) incl += u;
    }
    if (lane == 63) wsum[w] = incl;
    __syncthreads();
    if (t == 0) {
      int run = 0;
#pragma unroll
      for (int k = 0; k < 16; ++k) { woff[k] = run; run += wsum[k]; }
    }
    __syncthreads();
    int ebase = (incl - tsum) + woff[w] + carryS;
    if (i < NN) {
      int4 ov;
      ov.x = ebase;
      ov.y = ebase + dv.x;
      ov.z = ov.y + dv.y;
      ov.w = ov.z + dv.z;
      *reinterpret_cast<int4*>(off + i) = ov;
      *reinterpret_cast<int4*>(cur + i) = ov;
    }
    __syncthreads();
    if (t == 0) carryS += woff[15] + wsum[15];
    __syncthreads();
  }
}

__global__ __launch_bounds__(256) void k_fill(const int* __restrict__ src,
                                              const int* __restrict__ dst,
                                              int* __restrict__ cur,
                                              int* __restrict__ ssrc) {
  int e = blockIdx.x * 256 + threadIdx.x;  // grid = EE/256 exact
  int d = dst[e];
  int pos = atomicAdd(&cur[d], 1);
  ssrc[pos] = src[e];
}

// ============ aggregation: agg[i] = h[i] + sum_{j in in(i)} h[j] ============
// half-wave (32 lanes) per node, float4 per lane; unroll-8 for gather MLP.
__global__ __launch_bounds__(256) void k_agg(const float* __restrict__ h,
                                             const int* __restrict__ off,
                                             const int* __restrict__ deg,
                                             const int* __restrict__ ssrc,
                                             float* __restrict__ agg) {
  int node = blockIdx.x * 8 + (threadIdx.x >> 5);  // grid = NN/8 exact
  int lane = threadIdx.x & 31;
  int f = lane << 2;
  float4 acc = *reinterpret_cast<const float4*>(h + (size_t)node * FD + f);  // self
  int n = deg[node];
  const int* sl = ssrc + off[node];
  int j = 0;
  for (; j + 8 <= n; j += 8) {
    int s0 = sl[j], s1 = sl[j + 1], s2 = sl[j + 2], s3 = sl[j + 3];
    int s4 = sl[j + 4], s5 = sl[j + 5], s6 = sl[j + 6], s7 = sl[j + 7];
    float4 v0 = *reinterpret_cast<const float4*>(h + (size_t)s0 * FD + f);
    float4 v1 = *reinterpret_cast<const float4*>(h + (size_t)s1 * FD + f);
    float4 v2 = *reinterpret_cast<const float4*>(h + (size_t)s2 * FD + f);
    float4 v3 = *reinterpret_cast<const float4*>(h + (size_t)s3 * FD + f);
    float4 v4 = *reinterpret_cast<const float4*>(h + (size_t)s4 * FD + f);
    float4 v5 = *reinterpret_cast<const float4*>(h + (size_t)s5 * FD + f);
    float4 v6 = *reinterpret_cast<const float4*>(h + (size_t)s6 * FD + f);
    float4 v7 = *reinterpret_cast<const float4*>(h + (size_t)s7 * FD + f);
    float tx0 = (v0.x + v1.x) + (v2.x + v3.x);
    float ty0 = (v0.y + v1.y) + (v2.y + v3.y);
    float tz0 = (v0.z + v1.z) + (v2.z + v3.z);
    float tw0 = (v0.w + v1.w) + (v2.w + v3.w);
    float tx1 = (v4.x + v5.x) + (v6.x + v7.x);
    float ty1 = (v4.y + v5.y) + (v6.y + v7.y);
    float tz1 = (v4.z + v5.z) + (v6.z + v7.z);
    float tw1 = (v4.w + v5.w) + (v6.w + v7.w);
    acc.x += tx0 + tx1; acc.y += ty0 + ty1; acc.z += tz0 + tz1; acc.w += tw0 + tw1;
  }
  for (; j + 4 <= n; j += 4) {
    int s0 = sl[j], s1 = sl[j + 1], s2 = sl[j + 2], s3 = sl[j + 3];
    float4 v0 = *reinterpret_cast<const float4*>(h + (size_t)s0 * FD + f);
    float4 v1 = *reinterpret_cast<const float4*>(h + (size_t)s1 * FD + f);
    float4 v2 = *reinterpret_cast<const float4*>(h + (size_t)s2 * FD + f);
    float4 v3 = *reinterpret_cast<const float4*>(h + (size_t)s3 * FD + f);
    acc.x += (v0.x + v1.x) + (v2.x + v3.x);
    acc.y += (v0.y + v1.y) + (v2.y + v3.y);
    acc.z += (v0.z + v1.z) + (v2.z + v3.z);
    acc.w += (v0.w + v1.w) + (v2.w + v3.w);
  }
  for (; j < n; ++j) {
    int s = sl[j];
    float4 v = *reinterpret_cast<const float4*>(h + (size_t)s * FD + f);
    acc.x += v.x; acc.y += v.y; acc.z += v.z; acc.w += v.w;
  }
  *reinterpret_cast<float4*>(agg + (size_t)node * FD + f) = acc;
}

// ---------------- fused GEMM: O = relu(opt_bn(A @ W + b)) ----------------
// 128x128 tile per 256-thread block, 8x8 per thread, k-chunks of 32.
// LDS reads per k: a0/a1 conflict-free (banks 0,8,16,24 (+4)), w0/w1 2-way (free).
// At staging: each wave stores 64 consecutive rows per instr -> conflict-free.
__global__ __launch_bounds__(256) void k_gemm(const float* __restrict__ A,
                                              const float* __restrict__ W,
                                              const float* __restrict__ bias,
                                              const float* __restrict__ gg,
                                              const float* __restrict__ bb,
                                              const float* __restrict__ rm,
                                              const float* __restrict__ rv,
                                              int use_bn,
                                              float* __restrict__ O, int M) {
  __shared__ float At[32][132];  // [k][row], 128 rows + pad
  __shared__ float Ws[32][132];  // [k][col], 128 cols + pad
  const int t  = threadIdx.x;
  const int tx = t & 15;   // col group: cols tx*4..+3 and 64+tx*4..+3
  const int ty = t >> 4;   // row group: rows ty*8..+7
  const int rowBase = blockIdx.x * 128;

  float acc[8][8] = {};

  for (int kc = 0; kc < 4; ++kc) {
    const int k0 = kc << 5;
    // stage A transposed: fl -> (row = fl&127, kgroup = (fl>>7)*4)
#pragma unroll
    for (int i = 0; i < 4; ++i) {
      int fl = t + (i << 8);
      int row = fl & 127;
      int kg  = (fl >> 7) << 2;
      int r = rowBase + row;
      float4 v = make_float4(0.f, 0.f, 0.f, 0.f);
      if (r < M) v = *reinterpret_cast<const float4*>(A + (size_t)r * FD + k0 + kg);
      At[kg + 0][row] = v.x;
      At[kg + 1][row] = v.y;
      At[kg + 2][row] = v.z;
      At[kg + 3][row] = v.w;
    }
    // stage W: 32 k x 128 c
#pragma unroll
    for (int i = 0; i < 4; ++i) {
      int fl = t + (i << 8);
      int wr = fl >> 5;          // 0..31
      int wc = (fl & 31) << 2;   // 0..124
      *reinterpret_cast<float4*>(&Ws[wr][wc]) =
          *reinterpret_cast<const float4*>(W + (size_t)(k0 + wr) * FD + wc);
    }
    __syncthreads();

#pragma unroll 8
    for (int k = 0; k < 32; ++k) {
      const float4 a0 = *reinterpret_cast<const float4*>(&At[k][ty << 3]);
      const float4 a1 = *reinterpret_cast<const float4*>(&At[k][(ty << 3) + 4]);
      const float4 w0 = *reinterpret_cast<const float4*>(&Ws[k][tx << 2]);
      const float4 w1 = *reinterpret_cast<const float4*>(&Ws[k][64 + (tx << 2)]);
      const float av[8] = {a0.x, a0.y, a0.z, a0.w, a1.x, a1.y, a1.z, a1.w};
      const float wv[8] = {w0.x, w0.y, w0.z, w0.w, w1.x, w1.y, w1.z, w1.w};
#pragma unroll
      for (int i2 = 0; i2 < 8; ++i2)
#pragma unroll
        for (int j = 0; j < 8; ++j)
          acc[i2][j] = fmaf(av[i2], wv[j], acc[i2][j]);
    }
    __syncthreads();
  }

  // epilogue: fold bias (+ BN eval) + relu. cols: j<4 -> tx*4+j ; j>=4 -> 64+tx*4+j-4
  float sc[8], sh[8];
#pragma unroll
  for (int j = 0; j < 8; ++j) {
    int c = (j < 4) ? ((tx << 2) + j) : (64 + (tx << 2) + (j - 4));
    if (use_bn) {
      float s = gg[c] * rsqrtf(rv[c] + 1e-5f);
      sc[j] = s;
      sh[j] = (bias[c] - rm[c]) * s + bb[c];
    } else {
      sc[j] = 1.f;
      sh[j] = bias[c];
    }
  }
#pragma unroll
  for (int i = 0; i < 8; ++i) {
    int r = rowBase + (ty << 3) + i;
    if (r < M) {
      float o[8];
#pragma unroll
      for (int j = 0; j < 8; ++j) {
        float v = fmaf(acc[i][j], sc[j], sh[j]);
        o[j] = v > 0.f ? v : 0.f;
      }
      *reinterpret_cast<float4*>(O + (size_t)r * FD + (tx << 2)) =
          make_float4(o[0], o[1], o[2], o[3]);
      *reinterpret_cast<float4*>(O + (size_t)r * FD + 64 + (tx << 2)) =
          make_float4(o[4], o[5], o[6], o[7]);
    }
  }
}

// ---------------- U/V: per-node logit halves, half-wave per node ----------------
// h row read ONCE (float4/lane); 12 dots via lane-partials + 5-round shfl_xor reduce.
__global__ __launch_bounds__(256) void k_uv(const float* __restrict__ h,
                                            const float* __restrict__ clsW,
                                            float* __restrict__ U,
                                            float* __restrict__ V) {
  int node = blockIdx.x * 8 + (threadIdx.x >> 5);  // grid = NN/8 exact
  int lane = threadIdx.x & 31;
  int f = lane << 2;
  float4 v = *reinterpret_cast<const float4*>(h + (size_t)node * FD + f);
  float p[12];
#pragma unroll
  for (int c = 0; c < 6; ++c) {
    p[c] = fmaf(v.x, clsW[(size_t)(f + 0) * 6 + c],
           fmaf(v.y, clsW[(size_t)(f + 1) * 6 + c],
           fmaf(v.z, clsW[(size_t)(f + 2) * 6 + c],
                v.w * clsW[(size_t)(f + 3) * 6 + c])));
    p[6 + c] = fmaf(v.x, clsW[(size_t)(FD + f + 0) * 6 + c],
               fmaf(v.y, clsW[(size_t)(FD + f + 1) * 6 + c],
               fmaf(v.z, clsW[(size_t)(FD + f + 2) * 6 + c],
                    v.w * clsW[(size_t)(FD + f + 3) * 6 + c])));
  }
#pragma unroll
  for (int m = 16; m >= 1; m >>= 1) {
#pragma unroll
    for (int c = 0; c < 12; ++c) p[c] += __shfl_xor(p[c], m, 64);
  }
  // lane 0..5 -> U, lane 6..11 -> V (static-index select, no scratch)
  float outv = 0.f;
#pragma unroll
  for (int c = 0; c < 12; ++c) outv = (lane == c) ? p[c] : outv;
  if (lane < 6)       U[(size_t)node * 6 + lane] = outv;
  else if (lane < 12) V[(size_t)node * 6 + (lane - 6)] = outv;
}

// ---------------- edge kernel: e = [h[src], h[dst]]; logits = U[src]+V[dst]+b ----
__global__ __launch_bounds__(256) void k_edge(const float* __restrict__ h,
                                              const int* __restrict__ src,
                                              const int* __restrict__ dst,
                                              const float* __restrict__ U,
                                              const float* __restrict__ V,
                                              const float* __restrict__ clsB,
                                              float* __restrict__ outL,
                                              float* __restrict__ outE) {
  int eid  = blockIdx.x * 4 + (threadIdx.x >> 6);  // one wave per edge
  int lane = threadIdx.x & 63;
  int s = src[eid];
  int d = dst[eid];
  int node = (lane < 32) ? s : d;
  int f = (lane & 31) << 2;
  fvec4 v = *reinterpret_cast<const fvec4*>(h + (size_t)node * FD + f);
  __builtin_nontemporal_store(v, reinterpret_cast<fvec4*>(outE + (size_t)eid * 256 + (lane << 2)));
  if (lane < 6) {
    float lv = U[(size_t)s * 6 + lane] + V[(size_t)d * 6 + lane] + clsB[lane];
    __builtin_nontemporal_store(lv, outL + (size_t)eid * 6 + lane);
  }
}

extern "C" void kernel_launch(void* const* d_in, const int* in_sizes, int n_in,
                              void* d_out, int out_size, void* d_ws, size_t ws_size,
                              hipStream_t stream) {
  const float* x     = (const float*)d_in[0];
  const int*   ei    = (const int*)d_in[1];
  const int*   src   = ei;
  const int*   dst   = ei + EE;
  const float* c1_W1 = (const float*)d_in[3];
  const float* c1_b1 = (const float*)d_in[4];
  const float* c1_g  = (const float*)d_in[5];
  const float* c1_be = (const float*)d_in[6];
  const float* c1_rm = (const float*)d_in[7];
  const float* c1_rv = (const float*)d_in[8];
  const float* c1_W2 = (const float*)d_in[9];
  const float* c1_b2 = (const float*)d_in[10];
  const float* cv_W1 = (const float*)d_in[11];
  const float* cv_b1 = (const float*)d_in[12];
  const float* cv_g  = (const float*)d_in[13];
  const float* cv_be = (const float*)d_in[14];
  const float* cv_rm = (const float*)d_in[15];
  const float* cv_rv = (const float*)d_in[16];
  const float* cv_W2 = (const float*)d_in[17];
  const float* cv_b2 = (const float*)d_in[18];
  const float* ln_W  = (const float*)d_in[19];
  const float* ln_b  = (const float*)d_in[20];
  const float* clsW  = (const float*)d_in[21];
  const float* clsB  = (const float*)d_in[22];

  // workspace (unchanged verified layout, ~53.6 MB):
  float* buf0 = (float*)d_ws;
  float* buf1 = buf0 + (size_t)NN * FD;
  float* Uu   = buf1 + (size_t)NN * FD;
  float* Vv   = Uu + (size_t)NN * 6;

  float* outL = (float*)d_out;
  float* outE = outL + (size_t)EE * 6;

  // CSR scratch in tail of outE (dead until k_edge, which runs last)
  const size_t outFloats = (size_t)EE * 262;
  const size_t scrInts   = (size_t)NN * 3 + (size_t)EE;
  const size_t scrStart  = (outFloats - scrInts) & ~(size_t)3;  // 16B align
  int* deg  = (int*)d_out + scrStart;
  int* off  = deg + NN;
  int* curp = off + NN;
  int* ssrc = curp + NN;

  dim3 B(256);
  const int gZero   = (NN + 255) / 256;
  const int gEdgeWk = EE / 256;            // 2500 exact
  const int gAgg    = NN / 8;              // 6250 exact
  const int gGemm   = (NN + 127) / 128;    // 391
  const int gUV     = NN / 8;              // 6250 exact
  const int gEdge   = EE / 4;              // 160000 exact

  // ---- build CSR ----
  k_zero<<<gZero, B, 0, stream>>>(deg);
  k_hist<<<gEdgeWk, B, 0, stream>>>(dst, deg);
  k_scan<<<1, dim3(1024), 0, stream>>>(deg, off, curp);
  k_fill<<<gEdgeWk, B, 0, stream>>>(src, dst, curp, ssrc);

  float* bufs[2] = {buf0, buf1};

  // conv1
  k_agg<<<gAgg, B, 0, stream>>>(x, off, deg, ssrc, buf0);
  k_gemm<<<gGemm, B, 0, stream>>>(buf0, c1_W1, c1_b1, c1_g, c1_be, c1_rm, c1_rv, 1, buf1, NN);
  k_gemm<<<gGemm, B, 0, stream>>>(buf1, c1_W2, c1_b2, nullptr, nullptr, nullptr, nullptr, 0, buf0, NN);
  int pp = 0;

  // 2 more GIN layers
  for (int l = 0; l < 2; ++l) {
    float* hc = bufs[pp];
    float* ho = bufs[1 - pp];
    k_agg<<<gAgg, B, 0, stream>>>(hc, off, deg, ssrc, ho);
    k_gemm<<<gGemm, B, 0, stream>>>(ho, cv_W1 + (size_t)l * FD * FD, cv_b1 + l * FD,
                                    cv_g + l * FD, cv_be + l * FD, cv_rm + l * FD,
                                    cv_rv + l * FD, 1, hc, NN);
    k_gemm<<<gGemm, B, 0, stream>>>(hc, cv_W2 + (size_t)l * FD * FD, cv_b2 + l * FD,
                                    nullptr, nullptr, nullptr, nullptr, 0, ho, NN);
    pp = 1 - pp;
  }

  // 2 linear layers
  for (int l = 0; l < 2; ++l) {
    k_gemm<<<gGemm, B, 0, stream>>>(bufs[pp], ln_W + (size_t)l * FD * FD, ln_b + l * FD,
                                    nullptr, nullptr, nullptr, nullptr, 0, bufs[1 - pp], NN);
    pp = 1 - pp;
  }

  // classifier split + edge materialization
  k_uv<<<gUV, B, 0, stream>>>(bufs[pp], clsW, Uu, Vv);
  k_edge<<<gEdge, B, 0, stream>>>(bufs[pp], src, dst, Uu, Vv, clsB, outL, outE);
}